// Round 5
// baseline (740.069 us; speedup 1.0000x reference)
//
#include <hip/hip_runtime.h>

#define IN_F 1024
#define NVOC 32000
#define NTOK 8192
#define BM 128
#define BN 128
#define NT (NVOC / BN)   /* 250 n-tiles */
#define MT (NTOK / BM)   /* 64 m-tiles  */
#define NBLK (NT * MT)   /* 16000 blocks */
#define SMOOTH 0.1f

typedef __attribute__((ext_vector_type(8))) short short8;   // 8 bf16
typedef __attribute__((ext_vector_type(4))) float f32x4;    // MFMA acc
typedef __attribute__((ext_vector_type(8))) int int8v;      // 32B fp8 frag
typedef __attribute__((ext_vector_type(4))) int int4v;      // 16B LDS read
typedef unsigned int u32;

__device__ inline unsigned short f2bf(float f) {
  u32 u = __float_as_uint(f);
  return (unsigned short)((u + 0x7fffu + ((u >> 16) & 1u)) >> 16);
}

__device__ inline void gload_lds16(const void* g, void* l) {
  // async global->LDS, 16B per lane; LDS dest = wave-uniform base + lane*16
  __builtin_amdgcn_global_load_lds(
      (const __attribute__((address_space(1))) u32*)g,
      (__attribute__((address_space(3))) u32*)l, 16, 0, 0);
}

// ---------------------------------------------------------------------------
// prep: block 0 normalizes target indices (int64 vs int32 staging detect);
// all blocks grid-stride convert X and W fp32 -> fp8 e4m3 (OCP, HW RNE cvt).
// ---------------------------------------------------------------------------
__global__ void prep(const float4* __restrict__ x, const float4* __restrict__ w,
                     u32* __restrict__ x8, u32* __restrict__ w8,
                     const int* __restrict__ traw, int* __restrict__ tgtidx) {
  if (blockIdx.x == 0) {
    __shared__ int flag;
    if (threadIdx.x == 0) flag = 0;
    __syncthreads();
    int any = 0;
    for (int i = threadIdx.x; i < NTOK / 2; i += 256) any |= (traw[2 * i + 1] != 0);
    if (any) atomicOr(&flag, 1);
    __syncthreads();
    const int is64 = (flag == 0);
    for (int i = threadIdx.x; i < NTOK; i += 256)
      tgtidx[i] = is64 ? traw[2 * i] : traw[i];
  }
  const int gid = blockIdx.x * 256 + threadIdx.x;
  const int stride = gridDim.x * 256;
  for (int i = gid; i < NTOK * IN_F / 4; i += stride) {
    const float4 v = x[i];
    int p = __builtin_amdgcn_cvt_pk_fp8_f32(v.x, v.y, 0, false);
    p = __builtin_amdgcn_cvt_pk_fp8_f32(v.z, v.w, p, true);
    x8[i] = (u32)p;
  }
  for (int i = gid; i < NVOC * IN_F / 4; i += stride) {
    const float4 v = w[i];
    int p = __builtin_amdgcn_cvt_pk_fp8_f32(v.x, v.y, 0, false);
    p = __builtin_amdgcn_cvt_pk_fp8_f32(v.z, v.w, p, true);
    w8[i] = (u32)p;
  }
}

// ---------------------------------------------------------------------------
// K1: 128x128 logits tile via MX-fp8 MFMA (16x16x128, trivial scales=1.0),
// fused in-register row (sumexp, sumlog) + target-logit pick.
// LDS rows are 128 B = full K=128 fp8.
// Chunk placement: position u holds global chunk 2(u'&3)+(u'>>2), u'=u^(row&7).
// => frag reads land at positions (quad)^p and (4+quad)^p — the exact address
// pattern measured conflict-free in round 3 (round-4's (2q+b)^p pattern cost
// 3.3e7 conflict cycles). k-permutation is identical for A and B, so the dot
// product is unchanged. Round-2 lesson: never dynamically index acc regs.
// ---------------------------------------------------------------------------
__global__ __launch_bounds__(256, 3) void gemm_fp8(
    const char* __restrict__ X8, const char* __restrict__ W8,
    const float* __restrict__ bias, const int* __restrict__ tgtidx,
    float* __restrict__ psum, float* __restrict__ pslog,
    float* __restrict__ tgtlogit) {
  __shared__ char smem[33792];
  char* As = smem;                        // [128 rows][128 B] fp8 A tile (16 KB)
  char* Bs = smem + 16384;                // [128 rows][128 B] fp8 B tile (16 KB)
  float* biasS = (float*)(smem + 32768);  // [128]
  int* tgtS = (int*)(smem + 33280);       // [128] target col - n0
  float* redse = (float*)smem;            // epilogue alias: [2][128]
  float* redsl = (float*)(smem + 1024);   // epilogue alias: [2][128]

  const int tid = threadIdx.x;
  const int wave = tid >> 6, lane = tid & 63;
  const int wm = wave & 1, wn = wave >> 1;        // 2x2 wave grid, each 64x64
  const int quad = lane >> 4, l16 = lane & 15;

  // XCD-aware swizzle: xcd = lid&7 owns m-tile slab; 8 consecutive blocks
  // within an XCD share one n-tile (B hot in that XCD's L2).
  const int lid = blockIdx.x;
  const int xcd = lid & 7, seq = lid >> 3;
  const int mt = (xcd << 3) | (seq & 7);
  const int nb = seq >> 3;
  const int n0 = nb * BN, m0 = mt * BM;

  if (tid < BN) {
    biasS[tid] = bias[n0 + tid];
    tgtS[tid] = tgtidx[m0 + tid] - n0;
  }

  const f32x4 zero = {0.f, 0.f, 0.f, 0.f};
  f32x4 acc[4][4];
#pragma unroll
  for (int i = 0; i < 4; ++i)
#pragma unroll
    for (int j = 0; j < 4; ++j) acc[i][j] = zero;

  // staging: lane at position lc sources global chunk c = 2(u&3)+(u>>2),
  // u = lc^(row&7) — a permutation within the row's single 128B line.
  const int lr = lane >> 3, lc = lane & 7;
  const char* pA[4];
  const char* pB[4];
#pragma unroll
  for (int i = 0; i < 4; ++i) {
    const int row = wave * 32 + i * 8 + lr;
    const int u = lc ^ (row & 7);
    const int c = ((u & 3) << 1) | (u >> 2);
    pA[i] = X8 + (size_t)(m0 + row) * IN_F + c * 16;
    pB[i] = W8 + (size_t)(n0 + row) * IN_F + c * 16;
  }

  for (int kt = 0; kt < IN_F / 128; ++kt) {   // 8 iterations
    __syncthreads();  // previous compute done reading LDS
#pragma unroll
    for (int i = 0; i < 4; ++i) {
      const int R0 = wave * 32 + i * 8;  // wave-uniform LDS row base
      gload_lds16(pA[i], As + R0 * 128);
      gload_lds16(pB[i], Bs + R0 * 128);
      pA[i] += 128;
      pB[i] += 128;
    }
    __syncthreads();  // drains vmcnt(0)

    // B frags first (stay live across i), A frag per i (short liveness).
    // Position (4b+quad)^p holds chunk 2*quad+b (k bytes 32q+16b..+16).
    int8v bfv[4];
#pragma unroll
    for (int t = 0; t < 4; ++t) {
      const int br = wn * 64 + t * 16 + l16;
      const int s0 = (quad ^ (br & 7)) << 4;        // b=0 -> chunk 2q
      const int s1 = ((4 + quad) ^ (br & 7)) << 4;  // b=1 -> chunk 2q+1
      const int4v lo = *(const int4v*)(Bs + br * 128 + s0);
      const int4v hi = *(const int4v*)(Bs + br * 128 + s1);
      int8v f;
      f[0] = lo[0]; f[1] = lo[1]; f[2] = lo[2]; f[3] = lo[3];
      f[4] = hi[0]; f[5] = hi[1]; f[6] = hi[2]; f[7] = hi[3];
      bfv[t] = f;
    }
#pragma unroll
    for (int i = 0; i < 4; ++i) {
      const int ar = wm * 64 + i * 16 + l16;
      const int s0 = (quad ^ (ar & 7)) << 4;
      const int s1 = ((4 + quad) ^ (ar & 7)) << 4;
      const int4v lo = *(const int4v*)(As + ar * 128 + s0);
      const int4v hi = *(const int4v*)(As + ar * 128 + s1);
      int8v af;
      af[0] = lo[0]; af[1] = lo[1]; af[2] = lo[2]; af[3] = lo[3];
      af[4] = hi[0]; af[5] = hi[1]; af[6] = hi[2]; af[7] = hi[3];
#pragma unroll
      for (int j = 0; j < 4; ++j)
        acc[i][j] = __builtin_amdgcn_mfma_scale_f32_16x16x128_f8f6f4(
            af, bfv[j], acc[i][j], 0 /*A=fp8*/, 0 /*B=fp8*/,
            0, 0x7F7F7F7F, 0, 0x7F7F7F7F);  // e8m0 127 -> scale 1.0
    }
  }

  // ---- In-register epilogue (C/D layout: col=l16, row=quad*4+reg) --------
  __syncthreads();  // all frag reads done; As region reusable for red arrays

  const float bv0 = biasS[wn * 64 + 0 * 16 + l16];
  const float bv1 = biasS[wn * 64 + 1 * 16 + l16];
  const float bv2 = biasS[wn * 64 + 2 * 16 + l16];
  const float bv3 = biasS[wn * 64 + 3 * 16 + l16];

#pragma unroll
  for (int i = 0; i < 4; ++i) {
#pragma unroll
    for (int reg = 0; reg < 4; ++reg) {
      const int row = wm * 64 + i * 16 + quad * 4 + reg;  // 0..127 tile-local
      const float v0 = acc[i][0][reg] + bv0;
      const float v1 = acc[i][1][reg] + bv1;
      const float v2 = acc[i][2][reg] + bv2;
      const float v3 = acc[i][3][reg] + bv3;
      float se = __expf(v0) + __expf(v1) + __expf(v2) + __expf(v3);
      float sl = v0 + v1 + v2 + v3;
      se += __shfl_xor(se, 1); se += __shfl_xor(se, 2);
      se += __shfl_xor(se, 4); se += __shfl_xor(se, 8);
      sl += __shfl_xor(sl, 1); sl += __shfl_xor(sl, 2);
      sl += __shfl_xor(sl, 4); sl += __shfl_xor(sl, 8);
      if (l16 == 0) {
        redse[wn * 128 + row] = se;
        redsl[wn * 128 + row] = sl;
      }
      // target logit pick — COMPILE-TIME indices only.
      const int ct = tgtS[row];
      if (ct >= 0 && ct < BN && (ct >> 6) == wn && (ct & 15) == l16) {
        const int jj = (ct >> 4) & 3;
        const float tv = jj == 0 ? v0 : (jj == 1 ? v1 : (jj == 2 ? v2 : v3));
        tgtlogit[m0 + row] = tv;
      }
    }
  }
  __syncthreads();
  if (tid < BM) {
    const size_t idx = (size_t)(m0 + tid) * NT + nb;
    psum[idx] = redse[tid] + redse[128 + tid];
    pslog[idx] = redsl[tid] + redsl[128 + tid];
  }
}

// ---------------------------------------------------------------------------
// Fallback (ws too small for fp8 staging): bf16 in-loop-convert path.
// ---------------------------------------------------------------------------
__global__ void fix_target(const int* __restrict__ traw, int* __restrict__ tgtidx) {
  __shared__ int flag;
  if (threadIdx.x == 0) flag = 0;
  __syncthreads();
  int any = 0;
  for (int i = threadIdx.x; i < NTOK / 2; i += 256) any |= (traw[2 * i + 1] != 0);
  if (any) atomicOr(&flag, 1);
  __syncthreads();
  const int is64 = (flag == 0);
  for (int i = threadIdx.x; i < NTOK; i += 256)
    tgtidx[i] = is64 ? traw[2 * i] : traw[i];
}

__global__ __launch_bounds__(256) void gemm_fb(
    const float* __restrict__ X, const float* __restrict__ W,
    const float* __restrict__ bias, const int* __restrict__ tgtidx,
    float* __restrict__ psum, float* __restrict__ pslog,
    float* __restrict__ tgtlogit) {
  __shared__ char smem[33792];
  char* As = smem;
  char* Bs = smem + 16384;
  float* biasS = (float*)(smem + 32768);
  int* tgtS = (int*)(smem + 33280);
  float* redse = (float*)smem;
  float* redsl = (float*)(smem + 1024);

  const int tid = threadIdx.x;
  const int wave = tid >> 6, lane = tid & 63;
  const int wm = wave & 1, wn = wave >> 1;
  const int quad = lane >> 4, l16 = lane & 15;
  const int lid = blockIdx.x;
  const int xcd = lid & 7, seq = lid >> 3;
  const int mt = (xcd << 3) | (seq & 7);
  const int nb = seq >> 3;
  const int n0 = nb * BN, m0 = mt * BM;

  if (tid < BN) {
    biasS[tid] = bias[n0 + tid];
    tgtS[tid] = tgtidx[m0 + tid] - n0;
  }

  const f32x4 zero = {0.f, 0.f, 0.f, 0.f};
  f32x4 acc[4][4];
#pragma unroll
  for (int i = 0; i < 4; ++i)
#pragma unroll
    for (int j = 0; j < 4; ++j) acc[i][j] = zero;

  for (int kt = 0; kt < IN_F / 64; ++kt) {
    const int row = tid >> 1, hs = tid & 1;
    const float4* gA = (const float4*)(X + (size_t)(m0 + row) * IN_F + kt * 64 + hs * 32);
    const float4* gB = (const float4*)(W + (size_t)(n0 + row) * IN_F + kt * 64 + hs * 32);
    float4 a4[8], b4[8];
#pragma unroll
    for (int k = 0; k < 8; ++k) a4[k] = gA[k];
#pragma unroll
    for (int k = 0; k < 8; ++k) b4[k] = gB[k];
    __syncthreads();
#pragma unroll
    for (int cl = 0; cl < 4; ++cl) {
      const float4 x0 = a4[2 * cl], x1 = a4[2 * cl + 1];
      const float4 y0 = b4[2 * cl], y1 = b4[2 * cl + 1];
      short8 sa, sb;
      sa[0] = (short)f2bf(x0.x); sa[1] = (short)f2bf(x0.y);
      sa[2] = (short)f2bf(x0.z); sa[3] = (short)f2bf(x0.w);
      sa[4] = (short)f2bf(x1.x); sa[5] = (short)f2bf(x1.y);
      sa[6] = (short)f2bf(x1.z); sa[7] = (short)f2bf(x1.w);
      sb[0] = (short)f2bf(y0.x); sb[1] = (short)f2bf(y0.y);
      sb[2] = (short)f2bf(y0.z); sb[3] = (short)f2bf(y0.w);
      sb[4] = (short)f2bf(y1.x); sb[5] = (short)f2bf(y1.y);
      sb[6] = (short)f2bf(y1.z); sb[7] = (short)f2bf(y1.w);
      const int c = hs * 4 + cl;
      const int p = (c ^ (row & 7)) << 4;
      *(short8*)(As + row * 128 + p) = sa;
      *(short8*)(Bs + row * 128 + p) = sb;
    }
    __syncthreads();
#pragma unroll
    for (int kk = 0; kk < 2; ++kk) {
      short8 af[4], bfv[4];
#pragma unroll
      for (int t = 0; t < 4; ++t) {
        const int ar = wm * 64 + t * 16 + l16;
        af[t] = *(const short8*)(As + ar * 128 + ((((kk << 2) + quad) ^ (ar & 7)) << 4));
        const int br = wn * 64 + t * 16 + l16;
        bfv[t] = *(const short8*)(Bs + br * 128 + ((((kk << 2) + quad) ^ (br & 7)) << 4));
      }
#pragma unroll
      for (int i = 0; i < 4; ++i)
#pragma unroll
        for (int j = 0; j < 4; ++j)
          acc[i][j] = __builtin_amdgcn_mfma_f32_16x16x32_bf16(af[i], bfv[j], acc[i][j], 0, 0, 0);
    }
  }

  __syncthreads();
  const float bv0 = biasS[wn * 64 + 0 * 16 + l16];
  const float bv1 = biasS[wn * 64 + 1 * 16 + l16];
  const float bv2 = biasS[wn * 64 + 2 * 16 + l16];
  const float bv3 = biasS[wn * 64 + 3 * 16 + l16];
#pragma unroll
  for (int i = 0; i < 4; ++i) {
#pragma unroll
    for (int reg = 0; reg < 4; ++reg) {
      const int row = wm * 64 + i * 16 + quad * 4 + reg;
      const float v0 = acc[i][0][reg] + bv0;
      const float v1 = acc[i][1][reg] + bv1;
      const float v2 = acc[i][2][reg] + bv2;
      const float v3 = acc[i][3][reg] + bv3;
      float se = __expf(v0) + __expf(v1) + __expf(v2) + __expf(v3);
      float sl = v0 + v1 + v2 + v3;
      se += __shfl_xor(se, 1); se += __shfl_xor(se, 2);
      se += __shfl_xor(se, 4); se += __shfl_xor(se, 8);
      sl += __shfl_xor(sl, 1); sl += __shfl_xor(sl, 2);
      sl += __shfl_xor(sl, 4); sl += __shfl_xor(sl, 8);
      if (l16 == 0) {
        redse[wn * 128 + row] = se;
        redsl[wn * 128 + row] = sl;
      }
      const int ct = tgtS[row];
      if (ct >= 0 && ct < BN && (ct >> 6) == wn && (ct & 15) == l16) {
        const int jj = (ct >> 4) & 3;
        const float tv = jj == 0 ? v0 : (jj == 1 ? v1 : (jj == 2 ? v2 : v3));
        tgtlogit[m0 + row] = tv;
      }
    }
  }
  __syncthreads();
  if (tid < BM) {
    const size_t idx = (size_t)(m0 + tid) * NT + nb;
    psum[idx] = redse[tid] + redse[128 + tid];
    pslog[idx] = redsl[tid] + redsl[128 + tid];
  }
}

// ---------------------------------------------------------------------------
// K2: per-token merge over 250 tile-partials; block-reduce 4 tokens' losses
// and atomicAdd into d_out[0] (zeroed via memset node). finalsum deleted.
// ---------------------------------------------------------------------------
__global__ __launch_bounds__(256) void combine(
    const float* __restrict__ psum, const float* __restrict__ pslog,
    const float* __restrict__ tgtlogit, const int* __restrict__ tgtidx,
    float* __restrict__ out) {
  const int wv = threadIdx.x >> 6;
  const int token = blockIdx.x * 4 + wv;
  const int lane = threadIdx.x & 63;
  float se = 0.f, sl = 0.f;
  for (int l = lane; l < NT; l += 64) {
    const size_t idx = (size_t)token * NT + l;
    se += psum[idx];
    sl += pslog[idx];
  }
#pragma unroll
  for (int d = 1; d < 64; d <<= 1) {
    se += __shfl_xor(se, d);
    sl += __shfl_xor(sl, d);
  }
  __shared__ float bsum[4];
  if (lane == 0) {
    const int t = tgtidx[token];
    const float logZ = logf(se);
    const float nll = logZ - tgtlogit[token];
    const float smooth = (float)NVOC * logZ - sl;
    const float pt = (1.f - SMOOTH) * nll + (SMOOTH / (float)NVOC) * smooth;
    bsum[wv] = (t != 0) ? pt : 0.f;
  }
  __syncthreads();
  if (threadIdx.x == 0)
    atomicAdd(out, bsum[0] + bsum[1] + bsum[2] + bsum[3]);
}

extern "C" void kernel_launch(void* const* d_in, const int* in_sizes, int n_in,
                              void* d_out, int out_size, void* d_ws, size_t ws_size,
                              hipStream_t stream) {
  (void)in_sizes; (void)n_in; (void)out_size;
  const float* x = (const float*)d_in[0];
  const int* traw = (const int*)d_in[1];
  const float* w = (const float*)d_in[2];
  const float* bias = (const float*)d_in[3];

  char* ws = (char*)d_ws;
  float* psum = (float*)ws;
  float* pslog = psum + (size_t)NTOK * NT;
  float* tgtlogit = pslog + (size_t)NTOK * NT;
  int* tgtidx = (int*)(tgtlogit + NTOK);
  char* fraw = (char*)(tgtidx + NTOK);
  char* f8base = (char*)(((size_t)fraw + 15) & ~(size_t)15);
  const size_t base_need = (size_t)(f8base - ws);
  const size_t f8_need = (size_t)NTOK * IN_F + (size_t)NVOC * IN_F;  // 41 MB
  const bool pre8 = ws_size >= base_need + f8_need;

  hipMemsetAsync(d_out, 0, sizeof(float), stream);

  if (pre8) {
    char* x8 = f8base;
    char* w8 = x8 + (size_t)NTOK * IN_F;
    prep<<<8192, 256, 0, stream>>>((const float4*)x, (const float4*)w,
                                   (u32*)x8, (u32*)w8, traw, tgtidx);
    gemm_fp8<<<NBLK, 256, 0, stream>>>(x8, w8, bias, tgtidx, psum, pslog, tgtlogit);
  } else {
    fix_target<<<1, 256, 0, stream>>>(traw, tgtidx);
    gemm_fb<<<NBLK, 256, 0, stream>>>(x, w, bias, tgtidx, psum, pslog, tgtlogit);
  }
  combine<<<NTOK / 4, 256, 0, stream>>>(psum, pslog, tgtlogit, tgtidx, (float*)d_out);
}

// Round 6
// 657.779 us; speedup vs baseline: 1.1251x; 1.1251x over previous
//
#include <hip/hip_runtime.h>

#define IN_F 1024
#define NVOC 32000
#define NTOK 8192
#define BM 128
#define BN 128
#define NT (NVOC / BN)   /* 250 n-tiles */
#define MT (NTOK / BM)   /* 64 m-tiles  */
#define NBLK (NT * MT)   /* 16000 blocks */
#define SMOOTH 0.1f

typedef __attribute__((ext_vector_type(8))) short short8;   // 8 bf16
typedef __attribute__((ext_vector_type(4))) float f32x4;    // MFMA acc
typedef __attribute__((ext_vector_type(8))) int int8v;      // 32B fp8 frag
typedef __attribute__((ext_vector_type(4))) int int4v;      // 16B LDS read
typedef unsigned int u32;

__device__ inline unsigned short f2bf(float f) {
  u32 u = __float_as_uint(f);
  return (unsigned short)((u + 0x7fffu + ((u >> 16) & 1u)) >> 16);
}

__device__ inline void gload_lds16(const void* g, void* l) {
  // async global->LDS, 16B per lane; LDS dest = wave-uniform base + lane*16
  __builtin_amdgcn_global_load_lds(
      (const __attribute__((address_space(1))) u32*)g,
      (__attribute__((address_space(3))) u32*)l, 16, 0, 0);
}

// ---------------------------------------------------------------------------
// prep: block 0 normalizes target indices (int64 vs int32 staging detect);
// all blocks grid-stride convert X and W fp32 -> fp8 e4m3 (OCP, HW RNE cvt).
// ---------------------------------------------------------------------------
__global__ void prep(const float4* __restrict__ x, const float4* __restrict__ w,
                     u32* __restrict__ x8, u32* __restrict__ w8,
                     const int* __restrict__ traw, int* __restrict__ tgtidx) {
  if (blockIdx.x == 0) {
    __shared__ int flag;
    if (threadIdx.x == 0) flag = 0;
    __syncthreads();
    int any = 0;
    for (int i = threadIdx.x; i < NTOK / 2; i += 256) any |= (traw[2 * i + 1] != 0);
    if (any) atomicOr(&flag, 1);
    __syncthreads();
    const int is64 = (flag == 0);
    for (int i = threadIdx.x; i < NTOK; i += 256)
      tgtidx[i] = is64 ? traw[2 * i] : traw[i];
  }
  const int gid = blockIdx.x * 256 + threadIdx.x;
  const int stride = gridDim.x * 256;
  for (int i = gid; i < NTOK * IN_F / 4; i += stride) {
    const float4 v = x[i];
    int p = __builtin_amdgcn_cvt_pk_fp8_f32(v.x, v.y, 0, false);
    p = __builtin_amdgcn_cvt_pk_fp8_f32(v.z, v.w, p, true);
    x8[i] = (u32)p;
  }
  for (int i = gid; i < NVOC * IN_F / 4; i += stride) {
    const float4 v = w[i];
    int p = __builtin_amdgcn_cvt_pk_fp8_f32(v.x, v.y, 0, false);
    p = __builtin_amdgcn_cvt_pk_fp8_f32(v.z, v.w, p, true);
    w8[i] = (u32)p;
  }
}

// ---------------------------------------------------------------------------
// K1: 128x128 logits tile via MX-fp8 MFMA (16x16x128, trivial scales=1.0),
// fused in-register row (sumexp, sumlog) + target-logit pick.
// LDS rows are 128 B = full K=128 fp8.
// Chunk placement: position u holds global chunk 2(u'&3)+(u'>>2), u'=u^(row&7)
// => frag reads land at positions (quad)^p and (4+quad)^p — measured 0
// conflicts (round 5). k-permutation identical for A and B -> dot unchanged.
// Register discipline (rounds 2&5): never dynamically index acc; never give
// __launch_bounds__ a min-waves arg (acc AGPRs share the unified RF — a
// 3-waves/EU bound forced total<=170 regs and spilled acc -> 776 MB writes).
// ---------------------------------------------------------------------------
__global__ __launch_bounds__(256) void gemm_fp8(
    const char* __restrict__ X8, const char* __restrict__ W8,
    const float* __restrict__ bias, const int* __restrict__ tgtidx,
    float* __restrict__ psum, float* __restrict__ pslog,
    float* __restrict__ tgtlogit) {
  __shared__ char smem[33792];
  char* As = smem;                        // [128 rows][128 B] fp8 A tile (16 KB)
  char* Bs = smem + 16384;                // [128 rows][128 B] fp8 B tile (16 KB)
  float* biasS = (float*)(smem + 32768);  // [128]
  int* tgtS = (int*)(smem + 33280);       // [128] target col - n0
  float* redse = (float*)smem;            // epilogue alias: [2][128]
  float* redsl = (float*)(smem + 1024);   // epilogue alias: [2][128]

  const int tid = threadIdx.x;
  const int wave = tid >> 6, lane = tid & 63;
  const int wm = wave & 1, wn = wave >> 1;        // 2x2 wave grid, each 64x64
  const int quad = lane >> 4, l16 = lane & 15;

  // XCD-aware swizzle: xcd = lid&7 owns m-tile slab; 8 consecutive blocks
  // within an XCD share one n-tile (B hot in that XCD's L2).
  const int lid = blockIdx.x;
  const int xcd = lid & 7, seq = lid >> 3;
  const int mt = (xcd << 3) | (seq & 7);
  const int nb = seq >> 3;
  const int n0 = nb * BN, m0 = mt * BM;

  if (tid < BN) {
    biasS[tid] = bias[n0 + tid];
    tgtS[tid] = tgtidx[m0 + tid] - n0;
  }

  const f32x4 zero = {0.f, 0.f, 0.f, 0.f};
  f32x4 acc[4][4];
#pragma unroll
  for (int i = 0; i < 4; ++i)
#pragma unroll
    for (int j = 0; j < 4; ++j) acc[i][j] = zero;

  // staging: lane at position lc sources global chunk c = 2(u&3)+(u>>2),
  // u = lc^(row&7) — a permutation within the row's single 128B line.
  const int lr = lane >> 3, lc = lane & 7;
  const char* pA[4];
  const char* pB[4];
#pragma unroll
  for (int i = 0; i < 4; ++i) {
    const int row = wave * 32 + i * 8 + lr;
    const int u = lc ^ (row & 7);
    const int c = ((u & 3) << 1) | (u >> 2);
    pA[i] = X8 + (size_t)(m0 + row) * IN_F + c * 16;
    pB[i] = W8 + (size_t)(n0 + row) * IN_F + c * 16;
  }

  for (int kt = 0; kt < IN_F / 128; ++kt) {   // 8 iterations
    __syncthreads();  // previous compute done reading LDS
#pragma unroll
    for (int i = 0; i < 4; ++i) {
      const int R0 = wave * 32 + i * 8;  // wave-uniform LDS row base
      gload_lds16(pA[i], As + R0 * 128);
      gload_lds16(pB[i], Bs + R0 * 128);
      pA[i] += 128;
      pB[i] += 128;
    }
    __syncthreads();  // drains vmcnt(0)

    // B frags first (stay live across i), A frag per i (short liveness).
    // Position (4b+quad)^p holds chunk 2*quad+b (k bytes 32q+16b..+16).
    int8v bfv[4];
#pragma unroll
    for (int t = 0; t < 4; ++t) {
      const int br = wn * 64 + t * 16 + l16;
      const int s0 = (quad ^ (br & 7)) << 4;        // b=0 -> chunk 2q
      const int s1 = ((4 + quad) ^ (br & 7)) << 4;  // b=1 -> chunk 2q+1
      const int4v lo = *(const int4v*)(Bs + br * 128 + s0);
      const int4v hi = *(const int4v*)(Bs + br * 128 + s1);
      int8v f;
      f[0] = lo[0]; f[1] = lo[1]; f[2] = lo[2]; f[3] = lo[3];
      f[4] = hi[0]; f[5] = hi[1]; f[6] = hi[2]; f[7] = hi[3];
      bfv[t] = f;
    }
#pragma unroll
    for (int i = 0; i < 4; ++i) {
      const int ar = wm * 64 + i * 16 + l16;
      const int s0 = (quad ^ (ar & 7)) << 4;
      const int s1 = ((4 + quad) ^ (ar & 7)) << 4;
      const int4v lo = *(const int4v*)(As + ar * 128 + s0);
      const int4v hi = *(const int4v*)(As + ar * 128 + s1);
      int8v af;
      af[0] = lo[0]; af[1] = lo[1]; af[2] = lo[2]; af[3] = lo[3];
      af[4] = hi[0]; af[5] = hi[1]; af[6] = hi[2]; af[7] = hi[3];
#pragma unroll
      for (int j = 0; j < 4; ++j)
        acc[i][j] = __builtin_amdgcn_mfma_scale_f32_16x16x128_f8f6f4(
            af, bfv[j], acc[i][j], 0 /*A=fp8*/, 0 /*B=fp8*/,
            0, 0x7F7F7F7F, 0, 0x7F7F7F7F);  // e8m0 127 -> scale 1.0
    }
  }

  // ---- In-register epilogue (C/D layout: col=l16, row=quad*4+reg) --------
  __syncthreads();  // all frag reads done; As region reusable for red arrays

  const float bv0 = biasS[wn * 64 + 0 * 16 + l16];
  const float bv1 = biasS[wn * 64 + 1 * 16 + l16];
  const float bv2 = biasS[wn * 64 + 2 * 16 + l16];
  const float bv3 = biasS[wn * 64 + 3 * 16 + l16];

#pragma unroll
  for (int i = 0; i < 4; ++i) {
#pragma unroll
    for (int reg = 0; reg < 4; ++reg) {
      const int row = wm * 64 + i * 16 + quad * 4 + reg;  // 0..127 tile-local
      const float v0 = acc[i][0][reg] + bv0;
      const float v1 = acc[i][1][reg] + bv1;
      const float v2 = acc[i][2][reg] + bv2;
      const float v3 = acc[i][3][reg] + bv3;
      float se = __expf(v0) + __expf(v1) + __expf(v2) + __expf(v3);
      float sl = v0 + v1 + v2 + v3;
      se += __shfl_xor(se, 1); se += __shfl_xor(se, 2);
      se += __shfl_xor(se, 4); se += __shfl_xor(se, 8);
      sl += __shfl_xor(sl, 1); sl += __shfl_xor(sl, 2);
      sl += __shfl_xor(sl, 4); sl += __shfl_xor(sl, 8);
      if (l16 == 0) {
        redse[wn * 128 + row] = se;
        redsl[wn * 128 + row] = sl;
      }
      // target logit pick — COMPILE-TIME indices only.
      const int ct = tgtS[row];
      if (ct >= 0 && ct < BN && (ct >> 6) == wn && (ct & 15) == l16) {
        const int jj = (ct >> 4) & 3;
        const float tv = jj == 0 ? v0 : (jj == 1 ? v1 : (jj == 2 ? v2 : v3));
        tgtlogit[m0 + row] = tv;
      }
    }
  }
  __syncthreads();
  if (tid < BM) {
    const size_t idx = (size_t)(m0 + tid) * NT + nb;
    psum[idx] = redse[tid] + redse[128 + tid];
    pslog[idx] = redsl[tid] + redsl[128 + tid];
  }
}

// ---------------------------------------------------------------------------
// Fallback (ws too small for fp8 staging): bf16 in-loop-convert path.
// ---------------------------------------------------------------------------
__global__ void fix_target(const int* __restrict__ traw, int* __restrict__ tgtidx) {
  __shared__ int flag;
  if (threadIdx.x == 0) flag = 0;
  __syncthreads();
  int any = 0;
  for (int i = threadIdx.x; i < NTOK / 2; i += 256) any |= (traw[2 * i + 1] != 0);
  if (any) atomicOr(&flag, 1);
  __syncthreads();
  const int is64 = (flag == 0);
  for (int i = threadIdx.x; i < NTOK; i += 256)
    tgtidx[i] = is64 ? traw[2 * i] : traw[i];
}

__global__ __launch_bounds__(256) void gemm_fb(
    const float* __restrict__ X, const float* __restrict__ W,
    const float* __restrict__ bias, const int* __restrict__ tgtidx,
    float* __restrict__ psum, float* __restrict__ pslog,
    float* __restrict__ tgtlogit) {
  __shared__ char smem[33792];
  char* As = smem;
  char* Bs = smem + 16384;
  float* biasS = (float*)(smem + 32768);
  int* tgtS = (int*)(smem + 33280);
  float* redse = (float*)smem;
  float* redsl = (float*)(smem + 1024);

  const int tid = threadIdx.x;
  const int wave = tid >> 6, lane = tid & 63;
  const int wm = wave & 1, wn = wave >> 1;
  const int quad = lane >> 4, l16 = lane & 15;
  const int lid = blockIdx.x;
  const int xcd = lid & 7, seq = lid >> 3;
  const int mt = (xcd << 3) | (seq & 7);
  const int nb = seq >> 3;
  const int n0 = nb * BN, m0 = mt * BM;

  if (tid < BN) {
    biasS[tid] = bias[n0 + tid];
    tgtS[tid] = tgtidx[m0 + tid] - n0;
  }

  const f32x4 zero = {0.f, 0.f, 0.f, 0.f};
  f32x4 acc[4][4];
#pragma unroll
  for (int i = 0; i < 4; ++i)
#pragma unroll
    for (int j = 0; j < 4; ++j) acc[i][j] = zero;

  for (int kt = 0; kt < IN_F / 64; ++kt) {
    const int row = tid >> 1, hs = tid & 1;
    const float4* gA = (const float4*)(X + (size_t)(m0 + row) * IN_F + kt * 64 + hs * 32);
    const float4* gB = (const float4*)(W + (size_t)(n0 + row) * IN_F + kt * 64 + hs * 32);
    float4 a4[8], b4[8];
#pragma unroll
    for (int k = 0; k < 8; ++k) a4[k] = gA[k];
#pragma unroll
    for (int k = 0; k < 8; ++k) b4[k] = gB[k];
    __syncthreads();
#pragma unroll
    for (int cl = 0; cl < 4; ++cl) {
      const float4 x0 = a4[2 * cl], x1 = a4[2 * cl + 1];
      const float4 y0 = b4[2 * cl], y1 = b4[2 * cl + 1];
      short8 sa, sb;
      sa[0] = (short)f2bf(x0.x); sa[1] = (short)f2bf(x0.y);
      sa[2] = (short)f2bf(x0.z); sa[3] = (short)f2bf(x0.w);
      sa[4] = (short)f2bf(x1.x); sa[5] = (short)f2bf(x1.y);
      sa[6] = (short)f2bf(x1.z); sa[7] = (short)f2bf(x1.w);
      sb[0] = (short)f2bf(y0.x); sb[1] = (short)f2bf(y0.y);
      sb[2] = (short)f2bf(y0.z); sb[3] = (short)f2bf(y0.w);
      sb[4] = (short)f2bf(y1.x); sb[5] = (short)f2bf(y1.y);
      sb[6] = (short)f2bf(y1.z); sb[7] = (short)f2bf(y1.w);
      const int c = hs * 4 + cl;
      const int p = (c ^ (row & 7)) << 4;
      *(short8*)(As + row * 128 + p) = sa;
      *(short8*)(Bs + row * 128 + p) = sb;
    }
    __syncthreads();
#pragma unroll
    for (int kk = 0; kk < 2; ++kk) {
      short8 af[4], bfv[4];
#pragma unroll
      for (int t = 0; t < 4; ++t) {
        const int ar = wm * 64 + t * 16 + l16;
        af[t] = *(const short8*)(As + ar * 128 + ((((kk << 2) + quad) ^ (ar & 7)) << 4));
        const int br = wn * 64 + t * 16 + l16;
        bfv[t] = *(const short8*)(Bs + br * 128 + ((((kk << 2) + quad) ^ (br & 7)) << 4));
      }
#pragma unroll
      for (int i = 0; i < 4; ++i)
#pragma unroll
        for (int j = 0; j < 4; ++j)
          acc[i][j] = __builtin_amdgcn_mfma_f32_16x16x32_bf16(af[i], bfv[j], acc[i][j], 0, 0, 0);
    }
  }

  __syncthreads();
  const float bv0 = biasS[wn * 64 + 0 * 16 + l16];
  const float bv1 = biasS[wn * 64 + 1 * 16 + l16];
  const float bv2 = biasS[wn * 64 + 2 * 16 + l16];
  const float bv3 = biasS[wn * 64 + 3 * 16 + l16];
#pragma unroll
  for (int i = 0; i < 4; ++i) {
#pragma unroll
    for (int reg = 0; reg < 4; ++reg) {
      const int row = wm * 64 + i * 16 + quad * 4 + reg;
      const float v0 = acc[i][0][reg] + bv0;
      const float v1 = acc[i][1][reg] + bv1;
      const float v2 = acc[i][2][reg] + bv2;
      const float v3 = acc[i][3][reg] + bv3;
      float se = __expf(v0) + __expf(v1) + __expf(v2) + __expf(v3);
      float sl = v0 + v1 + v2 + v3;
      se += __shfl_xor(se, 1); se += __shfl_xor(se, 2);
      se += __shfl_xor(se, 4); se += __shfl_xor(se, 8);
      sl += __shfl_xor(sl, 1); sl += __shfl_xor(sl, 2);
      sl += __shfl_xor(sl, 4); sl += __shfl_xor(sl, 8);
      if (l16 == 0) {
        redse[wn * 128 + row] = se;
        redsl[wn * 128 + row] = sl;
      }
      const int ct = tgtS[row];
      if (ct >= 0 && ct < BN && (ct >> 6) == wn && (ct & 15) == l16) {
        const int jj = (ct >> 4) & 3;
        const float tv = jj == 0 ? v0 : (jj == 1 ? v1 : (jj == 2 ? v2 : v3));
        tgtlogit[m0 + row] = tv;
      }
    }
  }
  __syncthreads();
  if (tid < BM) {
    const size_t idx = (size_t)(m0 + tid) * NT + nb;
    psum[idx] = redse[tid] + redse[128 + tid];
    pslog[idx] = redsl[tid] + redsl[128 + tid];
  }
}

// ---------------------------------------------------------------------------
// K2: per-token merge over 250 tile-partials; block-reduce 4 tokens' losses
// and atomicAdd into d_out[0] (zeroed via memset node).
// ---------------------------------------------------------------------------
__global__ __launch_bounds__(256) void combine(
    const float* __restrict__ psum, const float* __restrict__ pslog,
    const float* __restrict__ tgtlogit, const int* __restrict__ tgtidx,
    float* __restrict__ out) {
  const int wv = threadIdx.x >> 6;
  const int token = blockIdx.x * 4 + wv;
  const int lane = threadIdx.x & 63;
  float se = 0.f, sl = 0.f;
  for (int l = lane; l < NT; l += 64) {
    const size_t idx = (size_t)token * NT + l;
    se += psum[idx];
    sl += pslog[idx];
  }
#pragma unroll
  for (int d = 1; d < 64; d <<= 1) {
    se += __shfl_xor(se, d);
    sl += __shfl_xor(sl, d);
  }
  __shared__ float bsum[4];
  if (lane == 0) {
    const int t = tgtidx[token];
    const float logZ = logf(se);
    const float nll = logZ - tgtlogit[token];
    const float smooth = (float)NVOC * logZ - sl;
    const float pt = (1.f - SMOOTH) * nll + (SMOOTH / (float)NVOC) * smooth;
    bsum[wv] = (t != 0) ? pt : 0.f;
  }
  __syncthreads();
  if (threadIdx.x == 0)
    atomicAdd(out, bsum[0] + bsum[1] + bsum[2] + bsum[3]);
}

extern "C" void kernel_launch(void* const* d_in, const int* in_sizes, int n_in,
                              void* d_out, int out_size, void* d_ws, size_t ws_size,
                              hipStream_t stream) {
  (void)in_sizes; (void)n_in; (void)out_size;
  const float* x = (const float*)d_in[0];
  const int* traw = (const int*)d_in[1];
  const float* w = (const float*)d_in[2];
  const float* bias = (const float*)d_in[3];

  char* ws = (char*)d_ws;
  float* psum = (float*)ws;
  float* pslog = psum + (size_t)NTOK * NT;
  float* tgtlogit = pslog + (size_t)NTOK * NT;
  int* tgtidx = (int*)(tgtlogit + NTOK);
  char* fraw = (char*)(tgtidx + NTOK);
  char* f8base = (char*)(((size_t)fraw + 15) & ~(size_t)15);
  const size_t base_need = (size_t)(f8base - ws);
  const size_t f8_need = (size_t)NTOK * IN_F + (size_t)NVOC * IN_F;  // 41 MB
  const bool pre8 = ws_size >= base_need + f8_need;

  hipMemsetAsync(d_out, 0, sizeof(float), stream);

  if (pre8) {
    char* x8 = f8base;
    char* w8 = x8 + (size_t)NTOK * IN_F;
    prep<<<8192, 256, 0, stream>>>((const float4*)x, (const float4*)w,
                                   (u32*)x8, (u32*)w8, traw, tgtidx);
    gemm_fp8<<<NBLK, 256, 0, stream>>>(x8, w8, bias, tgtidx, psum, pslog, tgtlogit);
  } else {
    fix_target<<<1, 256, 0, stream>>>(traw, tgtidx);
    gemm_fb<<<NBLK, 256, 0, stream>>>(x, w, bias, tgtidx, psum, pslog, tgtlogit);
  }
  combine<<<NTOK / 4, 256, 0, stream>>>(psum, pslog, tgtlogit, tgtidx, (float*)d_out);
}